// Round 12
// baseline (445.340 us; speedup 1.0000x reference)
//
#include <hip/hip_runtime.h>
#include <math.h>

#define NN 16384
#define EE 131072
#define ZZ 128
#define HH 8

typedef short bf16x8 __attribute__((ext_vector_type(8)));
typedef float f32x4 __attribute__((ext_vector_type(4)));
typedef unsigned short ushort4v __attribute__((ext_vector_type(4)));
typedef unsigned short ushort8v __attribute__((ext_vector_type(8)));

__device__ __forceinline__ float silu_f(float x) { return x / (1.0f + __expf(-x)); }

__device__ __forceinline__ unsigned short f2bf(float x) {
    unsigned u = __float_as_uint(x);
    unsigned r = (u >> 16) & 1u;
    u += 0x7fffu + r;
    return (unsigned short)(u >> 16);
}
__device__ __forceinline__ float bf2f(unsigned short x) {
    return __uint_as_float(((unsigned)x) << 16);
}

__device__ __forceinline__ f32x4 mfma16(bf16x8 a, bf16x8 b, f32x4 c) {
    return __builtin_amdgcn_mfma_f32_16x16x32_bf16(a, b, c, 0, 0, 0);
}

// stage a [128 x 128] bf16 tile (rows = output cols) from pre-transposed Wt
__device__ __forceinline__ void stageB(const unsigned short* Wt, char* lB, int t) {
    const uint4* Wg = (const uint4*)Wt;
#pragma unroll
    for (int i = 0; i < 8; ++i) {
        const int cid = t + i * 256;
        const int n = cid >> 4, c16 = cid & 15;
        *(uint4*)(lB + ((n * 256 + c16 * 16) ^ ((n & 7) << 4))) = Wg[cid];
    }
}

// ---- weight prep ----
struct WPrep {
    const float* w[13];
    int P[13];
    int tile0[14];
};

__global__ __launch_bounds__(128) void prep_weights(WPrep wp, unsigned short* wt) {
    int b = blockIdx.x, wi = 0;
    while (b >= wp.tile0[wi + 1]) ++wi;
    const int cg = (b - wp.tile0[wi]) * 128;
    const float* w = wp.w[wi];
    unsigned short* o = wt + (size_t)wp.tile0[wi] * 16384;
    const int P = wp.P[wi];
    const int t = threadIdx.x;
    for (int k0 = 0; k0 < 128; k0 += 8) {
        ushort8v v;
#pragma unroll
        for (int j = 0; j < 8; ++j) v[j] = f2bf(w[(size_t)(k0 + j) * P + cg + t]);
        *(ushort8v*)(o + (size_t)(cg + t) * 128 + k0) = v;
    }
}

struct BPrep {
    const float* b[13];
    int off[14];
};

__global__ __launch_bounds__(256) void prep_bias(BPrep bp, float* bcat) {
    const int idx = blockIdx.x * 256 + threadIdx.x;
    if (idx >= 2432) return;
    int wi = 0;
    while (idx >= bp.off[wi + 1]) ++wi;
    bcat[idx] = bp.b[wi] ? bp.b[wi][idx - bp.off[wi]] : 0.f;
}

__global__ __launch_bounds__(256) void prep_mub(const float* __restrict__ mu,
                                                unsigned short* __restrict__ mub) {
    const size_t idx = (size_t)blockIdx.x * 256 + threadIdx.x;
    const float4 a = ((const float4*)mu)[idx * 2];
    const float4 b = ((const float4*)mu)[idx * 2 + 1];
    ushort8v v;
    v[0] = f2bf(a.x); v[1] = f2bf(a.y); v[2] = f2bf(a.z); v[3] = f2bf(a.w);
    v[4] = f2bf(b.x); v[5] = f2bf(b.y); v[6] = f2bf(b.z); v[7] = f2bf(b.w);
    *(ushort8v*)(mub + idx * 8) = v;
}

// ---- bf16 MFMA GEMM: C[M x P] = act(A[M x 128] @ Wt^T + bias), bf16 out ----
template <int ACT, int INBF, int DUMP, int GATHERA>
__global__ __launch_bounds__(256, 2) void mm_bf16(
    const void* __restrict__ Av, const unsigned short* __restrict__ Wt,
    const float* __restrict__ bias, unsigned short* __restrict__ C,
    const unsigned short* __restrict__ aux, unsigned short* __restrict__ dumpA,
    const int* __restrict__ rowmap, int P, int As)
{
    __shared__ uint4 lA4[2048];
    __shared__ uint4 lB4[2048];
    char* lA = (char*)lA4;
    char* lB = (char*)lB4;
    const int t = threadIdx.x;
    const size_t row0 = (size_t)blockIdx.x * 128;
    const int cg = blockIdx.y * 128;
    if (INBF) {
        const uint4* Ag = (const uint4*)((const unsigned short*)Av + row0 * As);
        const int rs = As >> 3;
#pragma unroll
        for (int i = 0; i < 8; ++i) {
            const int chunk = t + i * 256;
            const int r = chunk >> 4, c16 = chunk & 15;
            *(uint4*)(lA + ((r * 256 + c16 * 16) ^ ((r & 7) << 4))) = Ag[r * rs + c16];
        }
    } else {
#pragma unroll
        for (int i = 0; i < 16; ++i) {
            const int f4 = t + i * 256;
            const int r = f4 >> 5, c4 = f4 & 31;
            const size_t gr = GATHERA ? (size_t)rowmap[row0 + r] : row0 + r;
            const float4 v = ((const float4*)((const float*)Av + gr * As))[c4];
            ushort4v bb;
            bb.x = f2bf(v.x); bb.y = f2bf(v.y); bb.z = f2bf(v.z); bb.w = f2bf(v.w);
            *(ushort4v*)(lA + ((r * 256 + c4 * 8) ^ ((r & 7) << 4))) = bb;
        }
    }
    stageB(Wt + (size_t)cg * 128, lB, t);
    __syncthreads();
    if (DUMP) {
#pragma unroll
        for (int i = 0; i < 8; ++i) {
            const int ch = t + i * 256;
            const int row = ch >> 4, cpos = ch & 15;
            const uint4 v = *(const uint4*)(lA + ((row * 256 + cpos * 16) ^ ((row & 7) << 4)));
            *(uint4*)(dumpA + (row0 + row) * 128 + cpos * 8) = v;
        }
    }
    const int lane = t & 63, wid = t >> 6;
    const int rbase = (wid >> 1) * 64, cbase = (wid & 1) * 64;
    const int lr = lane & 15, lgp = lane >> 4;
    f32x4 acc[4][4];
#pragma unroll
    for (int i = 0; i < 4; ++i)
#pragma unroll
        for (int j = 0; j < 4; ++j) acc[i][j] = (f32x4){0.f, 0.f, 0.f, 0.f};
#pragma unroll
    for (int ks = 0; ks < 4; ++ks) {
        bf16x8 av[4], bv[4];
#pragma unroll
        for (int mt = 0; mt < 4; ++mt) {
            const int r = rbase + mt * 16 + lr;
            av[mt] = *(const bf16x8*)(lA + ((r * 256 + ks * 64 + lgp * 16) ^ ((r & 7) << 4)));
        }
#pragma unroll
        for (int nt = 0; nt < 4; ++nt) {
            const int c = cbase + nt * 16 + lr;
            bv[nt] = *(const bf16x8*)(lB + ((c * 256 + ks * 64 + lgp * 16) ^ ((c & 7) << 4)));
        }
#pragma unroll
        for (int mt = 0; mt < 4; ++mt)
#pragma unroll
            for (int nt = 0; nt < 4; ++nt)
                acc[mt][nt] = mfma16(av[mt], bv[nt], acc[mt][nt]);
    }
    // epilogue: repack through LDS (lB free) -> coalesced stores
    __syncthreads();
#pragma unroll
    for (int nt = 0; nt < 4; ++nt) {
        const int col = cbase + nt * 16 + lr;
        const int gcol = cg + col;
        const float b = bias[gcol];
#pragma unroll
        for (int mt = 0; mt < 4; ++mt) {
#pragma unroll
            for (int j = 0; j < 4; ++j) {
                const int row = rbase + mt * 16 + lgp * 4 + j;
                float v = acc[mt][nt][j] + b;
                if (ACT == 1) v = silu_f(v);
                if (ACT == 2) v = v * bf2f(aux[(row0 + row) * (size_t)P + gcol]);
                *(unsigned short*)(lB + ((row * 256 + col * 2) ^ ((row & 7) << 4))) = f2bf(v);
            }
        }
    }
    __syncthreads();
#pragma unroll
    for (int i = 0; i < 8; ++i) {
        const int ch = t + i * 256;
        const int row = ch >> 4, cpos = ch & 15;
        const uint4 v = *(const uint4*)(lB + ((row * 256 + cpos * 16) ^ ((row & 7) << 4)));
        *(uint4*)(C + (row0 + row) * (size_t)P + cg + cpos * 8) = v;
    }
}

// ---- fused edge kernel: embp dump + phik(silu)->rabp + eu1(silu) + eu2->fup ----
// B matrices from global (L2-resident). One acc[4][4] live at a time.
// rabp stored via per-wave private scratch -> full-line 128B row stores.
__global__ __launch_bounds__(256, 3) void edge_mlp(
    const float* __restrict__ emb, const int* __restrict__ perm,
    const unsigned short* __restrict__ Wt_phik, const float* __restrict__ b_phik,
    const unsigned short* __restrict__ Wt1, const float* __restrict__ b1,
    const unsigned short* __restrict__ Wt2, const float* __restrict__ b2,
    unsigned short* __restrict__ embp, unsigned short* __restrict__ rabp,
    unsigned short* __restrict__ fup)
{
    __shared__ uint4 lA4[2048];
    __shared__ uint4 scr4[512];   // 8KB, 2KB/wave private
    char* lA = (char*)lA4;
    const int t = threadIdx.x;
    const size_t e0 = (size_t)blockIdx.x * 128;
    // stage emb[perm] -> lA (the pipeline's single reorder point)
#pragma unroll
    for (int i = 0; i < 16; ++i) {
        const int f4 = t + i * 256;
        const int r = f4 >> 5, c4 = f4 & 31;
        const size_t gr = (size_t)perm[e0 + r];
        const float4 v = ((const float4*)(emb + gr * 128))[c4];
        ushort4v bb;
        bb.x = f2bf(v.x); bb.y = f2bf(v.y); bb.z = f2bf(v.z); bb.w = f2bf(v.w);
        *(ushort4v*)(lA + ((r * 256 + c4 * 8) ^ ((r & 7) << 4))) = bb;
    }
    __syncthreads();
    // dump embp coalesced (full lines)
#pragma unroll
    for (int i = 0; i < 8; ++i) {
        const int ch = t + i * 256;
        const int row = ch >> 4, cpos = ch & 15;
        const uint4 v = *(const uint4*)(lA + ((row * 256 + cpos * 16) ^ ((row & 7) << 4)));
        *(uint4*)(embp + (e0 + row) * 128 + cpos * 8) = v;
    }
    const int lane = t & 63, wid = t >> 6;
    const int rbase = (wid >> 1) * 64, cbase = (wid & 1) * 64;
    const int lr = lane & 15, lgp = lane >> 4;
    char* swr = (char*)scr4 + wid * 2048;
    const int r2 = lane >> 3, c16r = lane & 7;
    f32x4 acc[4][4];
    // ---- GEMM-phik: silu(emb @ Wphik + b) -> rabp (wave-private repack) ----
#pragma unroll
    for (int i = 0; i < 4; ++i)
#pragma unroll
        for (int j = 0; j < 4; ++j) acc[i][j] = (f32x4){0.f, 0.f, 0.f, 0.f};
#pragma unroll
    for (int ks = 0; ks < 4; ++ks) {
        bf16x8 av[4], bv[4];
#pragma unroll
        for (int mt = 0; mt < 4; ++mt) {
            const int r = rbase + mt * 16 + lr;
            av[mt] = *(const bf16x8*)(lA + ((r * 256 + ks * 64 + lgp * 16) ^ ((r & 7) << 4)));
        }
#pragma unroll
        for (int nt = 0; nt < 4; ++nt)
            bv[nt] = *(const bf16x8*)(Wt_phik + (size_t)(cbase + nt * 16 + lr) * 128 + ks * 32 + lgp * 8);
#pragma unroll
        for (int mt = 0; mt < 4; ++mt)
#pragma unroll
            for (int nt = 0; nt < 4; ++nt)
                acc[mt][nt] = mfma16(bv[nt], av[mt], acc[mt][nt]);  // swapped: row via lr
    }
#pragma unroll
    for (int mt = 0; mt < 4; ++mt) {
#pragma unroll
        for (int nt = 0; nt < 4; ++nt) {
            const int wc = nt * 16 + lgp * 4;
            const float4 b4 = *(const float4*)(b_phik + cbase + wc);
            ushort4v st;
            st.x = f2bf(silu_f(acc[mt][nt][0] + b4.x));
            st.y = f2bf(silu_f(acc[mt][nt][1] + b4.y));
            st.z = f2bf(silu_f(acc[mt][nt][2] + b4.z));
            st.w = f2bf(silu_f(acc[mt][nt][3] + b4.w));
            *(ushort4v*)(swr + ((lr * 128 + wc * 2) ^ ((lr & 7) << 4))) = st;
        }
#pragma unroll
        for (int i = 0; i < 2; ++i) {
            const int rr = r2 + i * 8;
            const uint4 v = *(const uint4*)(swr + ((rr * 128 + c16r * 16) ^ ((rr & 7) << 4)));
            const size_t row_g = e0 + rbase + mt * 16 + rr;
            *(uint4*)(rabp + row_g * 128 + cbase + c16r * 8) = v;
        }
    }
    // ---- GEMM1: silu(emb @ Weu1 + b1) ----
#pragma unroll
    for (int i = 0; i < 4; ++i)
#pragma unroll
        for (int j = 0; j < 4; ++j) acc[i][j] = (f32x4){0.f, 0.f, 0.f, 0.f};
#pragma unroll
    for (int ks = 0; ks < 4; ++ks) {
        bf16x8 av[4], bv[4];
#pragma unroll
        for (int mt = 0; mt < 4; ++mt) {
            const int r = rbase + mt * 16 + lr;
            av[mt] = *(const bf16x8*)(lA + ((r * 256 + ks * 64 + lgp * 16) ^ ((r & 7) << 4)));
        }
#pragma unroll
        for (int nt = 0; nt < 4; ++nt)
            bv[nt] = *(const bf16x8*)(Wt1 + (size_t)(cbase + nt * 16 + lr) * 128 + ks * 32 + lgp * 8);
#pragma unroll
        for (int mt = 0; mt < 4; ++mt)
#pragma unroll
            for (int nt = 0; nt < 4; ++nt)
                acc[mt][nt] = mfma16(bv[nt], av[mt], acc[mt][nt]);
    }
    __syncthreads();   // all lA reads done -> safe to overwrite
    // repack silu(acc+b1) into lA (standard staging layout)
#pragma unroll
    for (int mt = 0; mt < 4; ++mt) {
        const int row = rbase + mt * 16 + lr;
#pragma unroll
        for (int nt = 0; nt < 4; ++nt) {
            const int col = cbase + nt * 16 + lgp * 4;
            const float4 b4 = *(const float4*)(b1 + col);
            ushort4v st;
            st.x = f2bf(silu_f(acc[mt][nt][0] + b4.x));
            st.y = f2bf(silu_f(acc[mt][nt][1] + b4.y));
            st.z = f2bf(silu_f(acc[mt][nt][2] + b4.z));
            st.w = f2bf(silu_f(acc[mt][nt][3] + b4.w));
            *(ushort4v*)(lA + ((row * 256 + col * 2) ^ ((row & 7) << 4))) = st;
        }
    }
    __syncthreads();
    // ---- GEMM2: (eu1out @ Weu2 + b2) -> fup ----
#pragma unroll
    for (int i = 0; i < 4; ++i)
#pragma unroll
        for (int j = 0; j < 4; ++j) acc[i][j] = (f32x4){0.f, 0.f, 0.f, 0.f};
#pragma unroll
    for (int ks = 0; ks < 4; ++ks) {
        bf16x8 av[4], bv[4];
#pragma unroll
        for (int mt = 0; mt < 4; ++mt) {
            const int r = rbase + mt * 16 + lr;
            av[mt] = *(const bf16x8*)(lA + ((r * 256 + ks * 64 + lgp * 16) ^ ((r & 7) << 4)));
        }
#pragma unroll
        for (int nt = 0; nt < 4; ++nt)
            bv[nt] = *(const bf16x8*)(Wt2 + (size_t)(cbase + nt * 16 + lr) * 128 + ks * 32 + lgp * 8);
#pragma unroll
        for (int mt = 0; mt < 4; ++mt)
#pragma unroll
            for (int nt = 0; nt < 4; ++nt)
                acc[mt][nt] = mfma16(bv[nt], av[mt], acc[mt][nt]);
    }
#pragma unroll
    for (int mt = 0; mt < 4; ++mt) {
#pragma unroll
        for (int nt = 0; nt < 4; ++nt) {
            const int wc = nt * 16 + lgp * 4;
            const float4 b4 = *(const float4*)(b2 + cbase + wc);
            ushort4v st;
            st.x = f2bf(acc[mt][nt][0] + b4.x);
            st.y = f2bf(acc[mt][nt][1] + b4.y);
            st.z = f2bf(acc[mt][nt][2] + b4.z);
            st.w = f2bf(acc[mt][nt][3] + b4.w);
            *(ushort4v*)(swr + ((lr * 128 + wc * 2) ^ ((lr & 7) << 4))) = st;
        }
#pragma unroll
        for (int i = 0; i < 2; ++i) {
            const int rr = r2 + i * 8;
            const uint4 v = *(const uint4*)(swr + ((rr * 128 + c16r * 16) ^ ((rr & 7) << 4)));
            const size_t row_g = e0 + rbase + mt * 16 + rr;
            *(uint4*)(fup + row_g * 128 + cbase + c16r * 8) = v;
        }
    }
}

// ---- per-node CSR attention; rabp & attnw slot-ordered (sequential) ----
__global__ __launch_bounds__(256) void attn_kernel(
    const int* __restrict__ row_start, const int* __restrict__ srcp,
    const unsigned short* __restrict__ qkb, const unsigned short* __restrict__ rabp,
    const float* __restrict__ ewp, float* __restrict__ attnw)
{
    const int t = threadIdx.x;
    const int n = blockIdx.x * 4 + (t >> 6);
    const int lane = t & 63;
    const int el = lane >> 3, h = lane & 7;
    const int beg = row_start[n], end = row_start[n + 1];
    if (beg == end) return;
    const ushort8v q0 = *(const ushort8v*)(qkb + (size_t)n * 256 + h * 16);
    const ushort8v q1 = *(const ushort8v*)(qkb + (size_t)n * 256 + h * 16 + 8);
    float m = -1e30f, den = 0.f;
    for (int i0 = beg; i0 < end; i0 += 8) {
        const int i = i0 + el;
        const bool valid = i < end;
        const int ii = valid ? i : beg;
        const int s = srcp[ii];
        const ushort8v k0 = *(const ushort8v*)(qkb + (size_t)s * 256 + 128 + h * 16);
        const ushort8v k1 = *(const ushort8v*)(qkb + (size_t)s * 256 + 128 + h * 16 + 8);
        const ushort8v r0 = *(const ushort8v*)(rabp + (size_t)ii * 128 + h * 16);
        const ushort8v r1 = *(const ushort8v*)(rabp + (size_t)ii * 128 + h * 16 + 8);
        float lgv = 0.f;
#pragma unroll
        for (int j = 0; j < 8; ++j) lgv += bf2f(q0[j]) * bf2f(k0[j]) * bf2f(r0[j]);
#pragma unroll
        for (int j = 0; j < 8; ++j) lgv += bf2f(q1[j]) * bf2f(k1[j]) * bf2f(r1[j]);
        if (!valid) lgv = -1e30f;
        else attnw[(size_t)i * 8 + h] = lgv;
        float cm = lgv;
        cm = fmaxf(cm, __shfl_xor(cm, 8));
        cm = fmaxf(cm, __shfl_xor(cm, 16));
        cm = fmaxf(cm, __shfl_xor(cm, 32));
        const float nm = fmaxf(m, cm);
        float ex = valid ? __expf(lgv - nm) : 0.f;
        float cd = ex;
        cd += __shfl_xor(cd, 8);
        cd += __shfl_xor(cd, 16);
        cd += __shfl_xor(cd, 32);
        den = den * __expf(m - nm) + cd;
        m = nm;
    }
    const float sc = sqrtf((float)(end - beg)) * 0.08838834764831845f / den;
    for (int i0 = beg; i0 < end; i0 += 8) {
        const int i = i0 + el;
        if (i >= end) continue;
        const float w = ewp[i];
        const float cut = (w < 5.0f) ? 0.5f * (cosf(w * 0.62831853071795864f) + 1.0f) : 0.0f;
        const float lgv = attnw[(size_t)i * 8 + h];
        attnw[(size_t)i * 8 + h] = __expf(lgv - m) * sc * cut;
    }
}

// ---- fused r_ij MFMA GEMM + x_ij epilogue, slot-sequential ----
// NO LDS A-staging: av fragments read directly from global embp (L1/L2-hot,
// 3x reuse per tile). LDS = 12.3KB -> high occupancy. No barriers in loop.
__global__ __launch_bounds__(256, 5) void combine_mfma(
    const unsigned short* __restrict__ embp, const unsigned short* __restrict__ Wt_re,
    const float* __restrict__ bre, const float* __restrict__ attnw,
    unsigned short* __restrict__ ob)
{
    __shared__ float attnS[128 * 8];
    __shared__ uint4 scr4[512];   // 8KB, 2KB per wave (private)
    const int t = threadIdx.x;
    const size_t e0 = (size_t)blockIdx.x * 128;
    ((float4*)attnS)[t] = ((const float4*)(attnw + e0 * 8))[t];
    __syncthreads();
    const int lane = t & 63, wid = t >> 6;
    const int rbase = (wid >> 1) * 64, cbase = (wid & 1) * 64;
    const int lr = lane & 15, lgp = lane >> 4;
    char* swr = (char*)scr4 + wid * 2048;
    const int r2 = lane >> 3, c16r = lane & 7;
    for (int cg3 = 0; cg3 < 3; ++cg3) {
        const unsigned short* Wp = Wt_re + (size_t)cg3 * 16384;
        f32x4 acc[4][4];
#pragma unroll
        for (int i = 0; i < 4; ++i)
#pragma unroll
            for (int j = 0; j < 4; ++j) acc[i][j] = (f32x4){0.f, 0.f, 0.f, 0.f};
#pragma unroll
        for (int ks = 0; ks < 4; ++ks) {
            bf16x8 av[4], bv[4];
#pragma unroll
            for (int mt = 0; mt < 4; ++mt)
                av[mt] = *(const bf16x8*)(embp + (e0 + rbase + mt * 16 + lr) * 128 + ks * 32 + lgp * 8);
#pragma unroll
            for (int nt = 0; nt < 4; ++nt)
                bv[nt] = *(const bf16x8*)(Wp + (size_t)(cbase + nt * 16 + lr) * 128 + ks * 32 + lgp * 8);
#pragma unroll
            for (int mt = 0; mt < 4; ++mt)
#pragma unroll
                for (int nt = 0; nt < 4; ++nt)
                    acc[mt][nt] = mfma16(bv[nt], av[mt], acc[mt][nt]);  // swapped: D[c][r]
        }
        const int cgo = cg3 * 128;
#pragma unroll
        for (int mt = 0; mt < 4; ++mt) {
            const int row = rbase + mt * 16 + lr;
            const float* aS = attnS + row * 8;
#pragma unroll
            for (int nt = 0; nt < 4; ++nt) {
                const int wc = nt * 16 + lgp * 4;
                const int gcol = cgo + cbase + wc;
                const float coef = aS[gcol / 48];
                const float4 b4 = *(const float4*)(bre + gcol);
                ushort4v st;
                st.x = f2bf((acc[mt][nt][0] + b4.x) * coef);
                st.y = f2bf((acc[mt][nt][1] + b4.y) * coef);
                st.z = f2bf((acc[mt][nt][2] + b4.z) * coef);
                st.w = f2bf((acc[mt][nt][3] + b4.w) * coef);
                *(ushort4v*)(swr + ((lr * 128 + wc * 2) ^ ((lr & 7) << 4))) = st;
            }
#pragma unroll
            for (int i = 0; i < 2; ++i) {
                const int rr = r2 + i * 8;
                const uint4 v = *(const uint4*)(swr + ((rr * 128 + c16r * 16) ^ ((rr & 7) << 4)));
                const size_t row_g = e0 + rbase + mt * 16 + rr;
                *(uint4*)(ob + row_g * 384 + cgo + cbase + c16r * 8) = v;
            }
        }
    }
}

// ---- fused (wd + w_dot GEMM + tanh/df), per-wave repack, full-line df stores ----
__global__ __launch_bounds__(256, 3) void wdot_fused(
    const unsigned short* __restrict__ w12, const int* __restrict__ srcp,
    const int* __restrict__ dstp, const float* __restrict__ evp,
    const unsigned short* __restrict__ Wt_lin, const float* __restrict__ bl,
    const unsigned short* __restrict__ embp, const unsigned short* __restrict__ fup,
    const int* __restrict__ perm, float* __restrict__ df)
{
    __shared__ uint4 lA4[2048];
    char* lA = (char*)lA4;
    const int t = threadIdx.x;
    const size_t e0 = (size_t)blockIdx.x * 128;
#pragma unroll
    for (int i = 0; i < 8; ++i) {
        const int chunk = t + i * 256;
        const int r = chunk >> 4, c8 = chunk & 15;
        const size_t slot = e0 + r;
        const int s = srcp[slot], d = dstp[slot];
        const float e0v = evp[slot * 3 + 0], e1v = evp[slot * 3 + 1], e2v = evp[slot * 3 + 2];
        const ushort8v a0 = *(const ushort8v*)(w12 + ((size_t)d * 3 + 0) * 256 + c8 * 8);
        const ushort8v a1 = *(const ushort8v*)(w12 + ((size_t)d * 3 + 1) * 256 + c8 * 8);
        const ushort8v a2 = *(const ushort8v*)(w12 + ((size_t)d * 3 + 2) * 256 + c8 * 8);
        const ushort8v c0 = *(const ushort8v*)(w12 + ((size_t)s * 3 + 0) * 256 + 128 + c8 * 8);
        const ushort8v c1 = *(const ushort8v*)(w12 + ((size_t)s * 3 + 1) * 256 + 128 + c8 * 8);
        const ushort8v c2 = *(const ushort8v*)(w12 + ((size_t)s * 3 + 2) * 256 + 128 + c8 * 8);
        ushort8v o;
#pragma unroll
        for (int j = 0; j < 8; ++j) {
            const float av = e0v * bf2f(a0[j]) + e1v * bf2f(a1[j]) + e2v * bf2f(a2[j]);
            const float bv = e0v * bf2f(c0[j]) + e1v * bf2f(c1[j]) + e2v * bf2f(c2[j]);
            o[j] = f2bf(av * bv);
        }
        *(ushort8v*)(lA + ((r * 256 + c8 * 16) ^ ((r & 7) << 4))) = o;
    }
    __syncthreads();
    const int lane = t & 63, wid = t >> 6;
    const int rbase = (wid >> 1) * 64, cbase = (wid & 1) * 64;
    const int lr = lane & 15, lgp = lane >> 4;
    f32x4 acc[4][4];
#pragma unroll
    for (int i = 0; i < 4; ++i)
#pragma unroll
        for (int j = 0; j < 4; ++j) acc[i][j] = (f32x4){0.f, 0.f, 0.f, 0.f};
#pragma unroll
    for (int ks = 0; ks < 4; ++ks) {
        bf16x8 av[4], bv[4];
#pragma unroll
        for (int mt = 0; mt < 4; ++mt) {
            const int r = rbase + mt * 16 + lr;
            av[mt] = *(const bf16x8*)(lA + ((r * 256 + ks * 64 + lgp * 16) ^ ((r & 7) << 4)));
        }
#pragma unroll
        for (int nt = 0; nt < 4; ++nt)
            bv[nt] = *(const bf16x8*)(Wt_lin + (size_t)(cbase + nt * 16 + lr) * 128 + ks * 32 + lgp * 8);
#pragma unroll
        for (int mt = 0; mt < 4; ++mt)
#pragma unroll
            for (int nt = 0; nt < 4; ++nt)
                acc[mt][nt] = mfma16(bv[nt], av[mt], acc[mt][nt]);  // swapped
    }
    __syncthreads();   // all waves done reading lA; reuse as private repack scratch
    char* swr = lA + wid * 8192;
    const int r2 = lane >> 2, c4 = lane & 3;
#pragma unroll
    for (int mt = 0; mt < 4; ++mt) {
#pragma unroll
        for (int nt = 0; nt < 4; ++nt) {
            const int wc = nt * 16 + lgp * 4;
            const float4 b4 = *(const float4*)(bl + cbase + wc);
            float4 v;
            v.x = tanhf(acc[mt][nt][0] + b4.x);
            v.y = tanhf(acc[mt][nt][1] + b4.y);
            v.z = tanhf(acc[mt][nt][2] + b4.z);
            v.w = tanhf(acc[mt][nt][3] + b4.w);
            *(float4*)(swr + ((lr * 256 + wc * 4) ^ ((lr & 7) << 4))) = v;
        }
#pragma unroll
        for (int i = 0; i < 4; ++i) {
            const int chunk = i * 4 + c4;
            const float4 v = *(const float4*)(swr + ((r2 * 256 + chunk * 16) ^ ((r2 & 7) << 4)));
            const int row = rbase + mt * 16 + r2;
            const size_t sbase = (e0 + row) * 128 + cbase + chunk * 4;
            const ushort4v em = *(const ushort4v*)(embp + sbase);
            const ushort4v fu = *(const ushort4v*)(fup + sbase);
            const size_t orow = (size_t)perm[e0 + row];
            float4 o;
            o.x = bf2f(em.x) + bf2f(fu.x) * v.x;
            o.y = bf2f(em.y) + bf2f(fu.y) * v.y;
            o.z = bf2f(em.z) + bf2f(fu.z) * v.z;
            o.w = bf2f(em.w) + bf2f(fu.w) * v.w;
            *(float4*)(df + orow * 128 + cbase + chunk * 4) = o;
        }
    }
}

// ---- CSR build ----
__global__ __launch_bounds__(256) void hist_kernel(const int* __restrict__ dst, int* __restrict__ counts) {
    const int e = blockIdx.x * 256 + threadIdx.x;
    atomicAdd(&counts[dst[e]], 1);
}

__global__ __launch_bounds__(256) void scan_kernel(const int* __restrict__ counts,
                                                   int* __restrict__ row_start,
                                                   int* __restrict__ cursor) {
    __shared__ int part[256];
    const int t = threadIdx.x;
    const int base = t * 64;
    int local[64];
    int s = 0;
#pragma unroll
    for (int i = 0; i < 64; ++i) { local[i] = s; s += counts[base + i]; }
    part[t] = s;
    __syncthreads();
    for (int off = 1; off < 256; off <<= 1) {
        int v = (t >= off) ? part[t - off] : 0;
        __syncthreads();
        part[t] += v;
        __syncthreads();
    }
    const int prev = (t == 0) ? 0 : part[t - 1];
#pragma unroll
    for (int i = 0; i < 64; ++i) {
        const int v = prev + local[i];
        row_start[base + i] = v;
        cursor[base + i] = v;
    }
    if (t == 255) row_start[NN] = prev + s;
}

// fill: perm + slot-ordered src/dst/ewt/ev
__global__ __launch_bounds__(256) void fill_kernel(
    const int* __restrict__ src, const int* __restrict__ dst,
    const float* __restrict__ ewt, const float* __restrict__ ev,
    int* __restrict__ cursor, int* __restrict__ perm, int* __restrict__ srcp,
    int* __restrict__ dstp, float* __restrict__ ewp, float* __restrict__ evp)
{
    const int e = blockIdx.x * 256 + threadIdx.x;
    const int d = dst[e];
    const int p = atomicAdd(&cursor[d], 1);
    perm[p] = e;
    srcp[p] = src[e];
    dstp[p] = d;
    ewp[p] = ewt[e];
    evp[p * 3 + 0] = ev[e * 3 + 0];
    evp[p * 3 + 1] = ev[e * 3 + 1];
    evp[p * 3 + 2] = ev[e * 3 + 2];
}

// ---- gather: 4 nodes/block, 64 lanes/node, 2 bf16 per lane (uint loads) ----
__global__ __launch_bounds__(256) void gather_kernel(
    const int* __restrict__ row_start, const int* __restrict__ srcp,
    const unsigned short* __restrict__ ob, const unsigned short* __restrict__ xv,
    const unsigned short* __restrict__ mub, const float* __restrict__ evp,
    const float* __restrict__ h_in, const float* __restrict__ mu_in,
    float* __restrict__ h_out, float* __restrict__ mu_out)
{
    const int n = blockIdx.x * 4 + (threadIdx.x >> 6);
    const int t2 = (threadIdx.x & 63) * 2;
    const int beg = row_start[n], end = row_start[n + 1];
    float2 h2 = *(const float2*)(h_in + (size_t)n * 128 + t2);
    float2 m0 = *(const float2*)(mu_in + (size_t)n * 384 + t2);
    float2 m1 = *(const float2*)(mu_in + (size_t)n * 384 + 128 + t2);
    float2 m2 = *(const float2*)(mu_in + (size_t)n * 384 + 256 + t2);
#define GSTEP(i)  { \
        const int s = srcp[i]; \
        const float ev0 = evp[(i) * 3 + 0], ev1 = evp[(i) * 3 + 1], ev2 = evp[(i) * 3 + 2]; \
        const unsigned op0 = *(const unsigned*)(ob + (size_t)(i) * 384 + t2); \
        const unsigned op1 = *(const unsigned*)(ob + (size_t)(i) * 384 + 128 + t2); \
        const unsigned op2 = *(const unsigned*)(ob + (size_t)(i) * 384 + 256 + t2); \
        const unsigned xp0 = *(const unsigned*)(xv + (size_t)s * 384 + t2); \
        const unsigned xp1 = *(const unsigned*)(xv + (size_t)s * 384 + 128 + t2); \
        const unsigned xp2 = *(const unsigned*)(xv + (size_t)s * 384 + 256 + t2); \
        const unsigned mp0 = *(const unsigned*)(mub + (size_t)s * 384 + t2); \
        const unsigned mp1 = *(const unsigned*)(mub + (size_t)s * 384 + 128 + t2); \
        const unsigned mp2 = *(const unsigned*)(mub + (size_t)s * 384 + 256 + t2); \
        const float os0 = bf2f((unsigned short)op0) * bf2f((unsigned short)xp0); \
        const float os1 = bf2f((unsigned short)(op0 >> 16)) * bf2f((unsigned short)(xp0 >> 16)); \
        const float od0 = bf2f((unsigned short)op1) * bf2f((unsigned short)xp1); \
        const float od1 = bf2f((unsigned short)(op1 >> 16)) * bf2f((unsigned short)(xp1 >> 16)); \
        const float ot0 = bf2f((unsigned short)op2) * bf2f((unsigned short)xp2); \
        const float ot1 = bf2f((unsigned short)(op2 >> 16)) * bf2f((unsigned short)(xp2 >> 16)); \
        h2.x += os0; h2.y += os1; \
        m0.x += od0 * ev0 + ot0 * bf2f((unsigned short)mp0); \
        m0.y += od1 * ev0 + ot1 * bf2f((unsigned short)(mp0 >> 16)); \
        m1.x += od0 * ev1 + ot0 * bf2f((unsigned short)mp1); \
        m1.y += od1 * ev1 + ot1 * bf2f((unsigned short)(mp1 >> 16)); \
        m2.x += od0 * ev2 + ot0 * bf2f((unsigned short)mp2); \
        m2.y += od1 * ev2 + ot1 * bf2f((unsigned short)(mp2 >> 16)); \
    }
    int i = beg;
    for (; i + 1 < end; i += 2) { GSTEP(i); GSTEP(i + 1); }
    if (i < end) GSTEP(i);
#undef GSTEP
    *(float2*)(h_out + (size_t)n * 128 + t2) = h2;
    *(float2*)(mu_out + (size_t)n * 384 + t2) = m0;
    *(float2*)(mu_out + (size_t)n * 384 + 128 + t2) = m1;
    *(float2*)(mu_out + (size_t)n * 384 + 256 + t2) = m2;
}

extern "C" void kernel_launch(void* const* d_in, const int* in_sizes, int n_in,
                              void* d_out, int out_size, void* d_ws, size_t ws_size,
                              hipStream_t stream) {
    const int* eidx = (const int*)d_in[0];
    const int* src = eidx;
    const int* dst = eidx + EE;
    const float* h_in  = (const float*)d_in[1];
    const float* mu_in = (const float*)d_in[2];
    const float* ev    = (const float*)d_in[3];
    const float* emb   = (const float*)d_in[4];
    const float* ewt   = (const float*)d_in[5];
    const float* W_q   = (const float*)d_in[7];  const float* b_q   = (const float*)d_in[8];
    const float* W_k   = (const float*)d_in[9];  const float* b_k   = (const float*)d_in[10];
    const float* W_gs1 = (const float*)d_in[11]; const float* b_gs1 = (const float*)d_in[12];
    const float* W_gs2 = (const float*)d_in[13]; const float* b_gs2 = (const float*)d_in[14];
    const float* W_gv1 = (const float*)d_in[15]; const float* b_gv1 = (const float*)d_in[16];
    const float* W_gv2 = (const float*)d_in[17]; const float* b_gv2 = (const float*)d_in[18];
    const float* W_phik= (const float*)d_in[19]; const float* b_phik= (const float*)d_in[20];
    const float* W_re  = (const float*)d_in[21]; const float* b_re  = (const float*)d_in[22];
    const float* W_vq  = (const float*)d_in[23];
    const float* W_vk0 = (const float*)d_in[24];
    const float* W_lin = (const float*)d_in[25]; const float* b_lin = (const float*)d_in[26];
    const float* W_eu1 = (const float*)d_in[27]; const float* b_eu1 = (const float*)d_in[28];
    const float* W_eu2 = (const float*)d_in[29]; const float* b_eu2 = (const float*)d_in[30];

    float* out    = (float*)d_out;
    float* h_out  = out;
    float* mu_out = out + (size_t)NN * ZZ;
    float* df     = out + (size_t)NN * ZZ * 4;

    const size_t NZ = (size_t)NN * ZZ, N3Z = (size_t)NN * 3 * ZZ, EZ = (size_t)EE * ZZ;
    const size_t EH = (size_t)EE * HH;
    char* p = (char*)d_ws;
    unsigned short* qkb   = (unsigned short*)p; p += NZ * 2 * 2;   // N x 256 (q|k)
    unsigned short* tmpn2 = (unsigned short*)p; p += NZ * 2 * 2;   // N x 256 (gs1|gv1)
    unsigned short* x3b   = (unsigned short*)p; p += N3Z * 2;      // N x 384
    unsigned short* xv    = (unsigned short*)p; p += N3Z * 2;      // N x 384
    unsigned short* mub   = (unsigned short*)p; p += N3Z * 2;      // N x 384 bf16 mu
    unsigned short* w12   = (unsigned short*)p; p += N3Z * 2 * 2;  // 3N x 256 (w1|w2)
    unsigned short* embp  = (unsigned short*)p; p += EZ * 2;       // slot-order bf16 emb
    unsigned short* rabp  = (unsigned short*)p; p += EZ * 2;       // slot-order r_attn
    unsigned short* fup   = (unsigned short*)p; p += EZ * 2;       // slot-order f_up
    unsigned short* ob    = (unsigned short*)p; p += EZ * 3 * 2;   // E x 384 slot-order
    float* attnw          = (float*)p;          p += EH * 4;       // slot-indexed coef
    unsigned short* wt    = (unsigned short*)p; p += 2432 * 128 * 2;
    float* bcat           = (float*)p;          p += 2432 * 4;
    int* counts           = (int*)p;            p += NN * 4;
    int* cursor           = (int*)p;            p += NN * 4;
    int* row_start        = (int*)p;            p += (NN + 1) * 4;
    int* perm             = (int*)p;            p += EE * 4;
    int* srcp             = (int*)p;            p += EE * 4;
    int* dstp             = (int*)p;            p += EE * 4;
    float* ewp            = (float*)p;          p += EE * 4;
    float* evp            = (float*)p;          p += EE * 12;

    // pool order: q,k,gs1,gv1,gs2,gv2,phik,re,vq,vk0,lin,eu1,eu2
    const float* wsrc[13] = {W_q, W_k, W_gs1, W_gv1, W_gs2, W_gv2, W_phik,
                             W_re, W_vq, W_vk0, W_lin, W_eu1, W_eu2};
    const float* bsrc[13] = {b_q, b_k, b_gs1, b_gv1, b_gs2, b_gv2, b_phik,
                             b_re, nullptr, nullptr, b_lin, b_eu1, b_eu2};
    const int Ps[13] = {128, 128, 128, 128, 384, 384, 128, 384, 128, 128, 128, 128, 128};
    WPrep wp; BPrep bp;
    int tiles = 0;
    for (int i = 0; i < 13; ++i) {
        wp.w[i] = wsrc[i]; wp.P[i] = Ps[i]; wp.tile0[i] = tiles;
        bp.b[i] = bsrc[i]; bp.off[i] = tiles * 128;
        tiles += Ps[i] / 128;
    }
    wp.tile0[13] = tiles; bp.off[13] = tiles * 128;
    unsigned short* wT[13]; const float* bC[13];
    for (int i = 0; i < 13; ++i) { wT[i] = wt + (size_t)wp.tile0[i] * 16384; bC[i] = bcat + bp.off[i]; }

    dim3 blk(256);
    prep_weights<<<dim3(tiles), dim3(128), 0, stream>>>(wp, wt);
    prep_bias<<<dim3(10), blk, 0, stream>>>(bp, bcat);
    prep_mub<<<dim3(N3Z / 8 / 256), blk, 0, stream>>>(mu_in, mub);
    // CSR build first (edge pipeline is slot-ordered from the source)
    hipMemsetAsync(counts, 0, NN * 4, stream);
    hist_kernel<<<dim3(EE/256), blk, 0, stream>>>(dst, counts);
    scan_kernel<<<dim3(1), blk, 0, stream>>>(counts, row_start, cursor);
    fill_kernel<<<dim3(EE/256), blk, 0, stream>>>(src, dst, ewt, ev, cursor, perm, srcp, dstp, ewp, evp);
    // node-side GEMMs (merged)
    mm_bf16<0,0,0,0><<<dim3(NN/128, 2), blk, 0, stream>>>(h_in, wT[0], bC[0], qkb, nullptr, nullptr, nullptr, 256, 128);
    mm_bf16<1,0,0,0><<<dim3(NN/128, 2), blk, 0, stream>>>(h_in, wT[2], bC[2], tmpn2, nullptr, nullptr, nullptr, 256, 128);
    mm_bf16<0,1,0,0><<<dim3(NN/128, 3), blk, 0, stream>>>(tmpn2, wT[4], bC[4], x3b, nullptr, nullptr, nullptr, 384, 256);
    mm_bf16<2,1,0,0><<<dim3(NN/128, 3), blk, 0, stream>>>(tmpn2 + 128, wT[5], bC[5], xv, x3b, nullptr, nullptr, 384, 256);
    // edge-side: fused embp dump + phik + eu1 + eu2 (single reorder point)
    edge_mlp<<<dim3(EE/128), blk, 0, stream>>>(
        emb, perm, wT[6], bC[6], wT[11], bC[11], wT[12], bC[12], embp, rabp, fup);
    // per-node CSR attention -> slot coef (all sequential)
    attn_kernel<<<dim3(NN/4), blk, 0, stream>>>(row_start, srcp, qkb, rabp, ewp, attnw);
    // fused r_ij GEMM + x_ij epilogue (no LDS A-staging, high occupancy)
    combine_mfma<<<dim3(EE/128), blk, 0, stream>>>(embp, wT[7], bC[7], attnw, ob);
    // atomic-free gather: sequential ob stream, 2-wide lanes
    gather_kernel<<<dim3(NN/4), blk, 0, stream>>>(
        row_start, srcp, ob, xv, mub, evp, h_in, mu_in, h_out, mu_out);
    // vector branch: merged vq|vk0, then wdot (df scattered full-line rows via perm)
    mm_bf16<0,0,0,0><<<dim3(3*NN/128, 2), blk, 0, stream>>>(mu_out, wT[8], bC[8], w12, nullptr, nullptr, nullptr, 256, 128);
    wdot_fused<<<dim3(EE/128), blk, 0, stream>>>(
        w12, srcp, dstp, evp, wT[10], bC[10], embp, fup, perm, df);
}

// Round 13
// 371.958 us; speedup vs baseline: 1.1973x; 1.1973x over previous
//
#include <hip/hip_runtime.h>
#include <math.h>

#define NN 16384
#define EE 131072
#define ZZ 128
#define HH 8

typedef short bf16x8 __attribute__((ext_vector_type(8)));
typedef float f32x4 __attribute__((ext_vector_type(4)));
typedef unsigned short ushort4v __attribute__((ext_vector_type(4)));
typedef unsigned short ushort8v __attribute__((ext_vector_type(8)));

__device__ __forceinline__ float silu_f(float x) { return x / (1.0f + __expf(-x)); }

__device__ __forceinline__ unsigned short f2bf(float x) {
    unsigned u = __float_as_uint(x);
    unsigned r = (u >> 16) & 1u;
    u += 0x7fffu + r;
    return (unsigned short)(u >> 16);
}
__device__ __forceinline__ float bf2f(unsigned short x) {
    return __uint_as_float(((unsigned)x) << 16);
}

__device__ __forceinline__ f32x4 mfma16(bf16x8 a, bf16x8 b, f32x4 c) {
    return __builtin_amdgcn_mfma_f32_16x16x32_bf16(a, b, c, 0, 0, 0);
}

// stage a [128 x 128] bf16 tile (rows = output cols) from pre-transposed Wt
__device__ __forceinline__ void stageB(const unsigned short* Wt, char* lB, int t) {
    const uint4* Wg = (const uint4*)Wt;
#pragma unroll
    for (int i = 0; i < 8; ++i) {
        const int cid = t + i * 256;
        const int n = cid >> 4, c16 = cid & 15;
        *(uint4*)(lB + ((n * 256 + c16 * 16) ^ ((n & 7) << 4))) = Wg[cid];
    }
}

// ---- weight prep ----
struct WPrep {
    const float* w[13];
    int P[13];
    int tile0[14];
};

__global__ __launch_bounds__(128) void prep_weights(WPrep wp, unsigned short* wt) {
    int b = blockIdx.x, wi = 0;
    while (b >= wp.tile0[wi + 1]) ++wi;
    const int cg = (b - wp.tile0[wi]) * 128;
    const float* w = wp.w[wi];
    unsigned short* o = wt + (size_t)wp.tile0[wi] * 16384;
    const int P = wp.P[wi];
    const int t = threadIdx.x;
    for (int k0 = 0; k0 < 128; k0 += 8) {
        ushort8v v;
#pragma unroll
        for (int j = 0; j < 8; ++j) v[j] = f2bf(w[(size_t)(k0 + j) * P + cg + t]);
        *(ushort8v*)(o + (size_t)(cg + t) * 128 + k0) = v;
    }
}

struct BPrep {
    const float* b[13];
    int off[14];
};

__global__ __launch_bounds__(256) void prep_bias(BPrep bp, float* bcat) {
    const int idx = blockIdx.x * 256 + threadIdx.x;
    if (idx >= 2432) return;
    int wi = 0;
    while (idx >= bp.off[wi + 1]) ++wi;
    bcat[idx] = bp.b[wi] ? bp.b[wi][idx - bp.off[wi]] : 0.f;
}

__global__ __launch_bounds__(256) void prep_mub(const float* __restrict__ mu,
                                                unsigned short* __restrict__ mub) {
    const size_t idx = (size_t)blockIdx.x * 256 + threadIdx.x;
    const float4 a = ((const float4*)mu)[idx * 2];
    const float4 b = ((const float4*)mu)[idx * 2 + 1];
    ushort8v v;
    v[0] = f2bf(a.x); v[1] = f2bf(a.y); v[2] = f2bf(a.z); v[3] = f2bf(a.w);
    v[4] = f2bf(b.x); v[5] = f2bf(b.y); v[6] = f2bf(b.z); v[7] = f2bf(b.w);
    *(ushort8v*)(mub + idx * 8) = v;
}

// ---- bf16 MFMA GEMM: C[M x P] = act(A[M x 128] @ Wt^T + bias), bf16 out ----
template <int ACT, int INBF, int DUMP, int GATHERA>
__global__ __launch_bounds__(256, 2) void mm_bf16(
    const void* __restrict__ Av, const unsigned short* __restrict__ Wt,
    const float* __restrict__ bias, unsigned short* __restrict__ C,
    const unsigned short* __restrict__ aux, unsigned short* __restrict__ dumpA,
    const int* __restrict__ rowmap, int P, int As)
{
    __shared__ uint4 lA4[2048];
    __shared__ uint4 lB4[2048];
    char* lA = (char*)lA4;
    char* lB = (char*)lB4;
    const int t = threadIdx.x;
    const size_t row0 = (size_t)blockIdx.x * 128;
    const int cg = blockIdx.y * 128;
    if (INBF) {
        const uint4* Ag = (const uint4*)((const unsigned short*)Av + row0 * As);
        const int rs = As >> 3;
#pragma unroll
        for (int i = 0; i < 8; ++i) {
            const int chunk = t + i * 256;
            const int r = chunk >> 4, c16 = chunk & 15;
            *(uint4*)(lA + ((r * 256 + c16 * 16) ^ ((r & 7) << 4))) = Ag[r * rs + c16];
        }
    } else {
#pragma unroll
        for (int i = 0; i < 16; ++i) {
            const int f4 = t + i * 256;
            const int r = f4 >> 5, c4 = f4 & 31;
            const size_t gr = GATHERA ? (size_t)rowmap[row0 + r] : row0 + r;
            const float4 v = ((const float4*)((const float*)Av + gr * As))[c4];
            ushort4v bb;
            bb.x = f2bf(v.x); bb.y = f2bf(v.y); bb.z = f2bf(v.z); bb.w = f2bf(v.w);
            *(ushort4v*)(lA + ((r * 256 + c4 * 8) ^ ((r & 7) << 4))) = bb;
        }
    }
    stageB(Wt + (size_t)cg * 128, lB, t);
    __syncthreads();
    if (DUMP) {
#pragma unroll
        for (int i = 0; i < 8; ++i) {
            const int ch = t + i * 256;
            const int row = ch >> 4, cpos = ch & 15;
            const uint4 v = *(const uint4*)(lA + ((row * 256 + cpos * 16) ^ ((row & 7) << 4)));
            *(uint4*)(dumpA + (row0 + row) * 128 + cpos * 8) = v;
        }
    }
    const int lane = t & 63, wid = t >> 6;
    const int rbase = (wid >> 1) * 64, cbase = (wid & 1) * 64;
    const int lr = lane & 15, lgp = lane >> 4;
    f32x4 acc[4][4];
#pragma unroll
    for (int i = 0; i < 4; ++i)
#pragma unroll
        for (int j = 0; j < 4; ++j) acc[i][j] = (f32x4){0.f, 0.f, 0.f, 0.f};
#pragma unroll
    for (int ks = 0; ks < 4; ++ks) {
        bf16x8 av[4], bv[4];
#pragma unroll
        for (int mt = 0; mt < 4; ++mt) {
            const int r = rbase + mt * 16 + lr;
            av[mt] = *(const bf16x8*)(lA + ((r * 256 + ks * 64 + lgp * 16) ^ ((r & 7) << 4)));
        }
#pragma unroll
        for (int nt = 0; nt < 4; ++nt) {
            const int c = cbase + nt * 16 + lr;
            bv[nt] = *(const bf16x8*)(lB + ((c * 256 + ks * 64 + lgp * 16) ^ ((c & 7) << 4)));
        }
#pragma unroll
        for (int mt = 0; mt < 4; ++mt)
#pragma unroll
            for (int nt = 0; nt < 4; ++nt)
                acc[mt][nt] = mfma16(av[mt], bv[nt], acc[mt][nt]);
    }
    // epilogue: repack through LDS (lB free) -> coalesced stores
    __syncthreads();
#pragma unroll
    for (int nt = 0; nt < 4; ++nt) {
        const int col = cbase + nt * 16 + lr;
        const int gcol = cg + col;
        const float b = bias[gcol];
#pragma unroll
        for (int mt = 0; mt < 4; ++mt) {
#pragma unroll
            for (int j = 0; j < 4; ++j) {
                const int row = rbase + mt * 16 + lgp * 4 + j;
                float v = acc[mt][nt][j] + b;
                if (ACT == 1) v = silu_f(v);
                if (ACT == 2) v = v * bf2f(aux[(row0 + row) * (size_t)P + gcol]);
                *(unsigned short*)(lB + ((row * 256 + col * 2) ^ ((row & 7) << 4))) = f2bf(v);
            }
        }
    }
    __syncthreads();
#pragma unroll
    for (int i = 0; i < 8; ++i) {
        const int ch = t + i * 256;
        const int row = ch >> 4, cpos = ch & 15;
        const uint4 v = *(const uint4*)(lB + ((row * 256 + cpos * 16) ^ ((row & 7) << 4)));
        *(uint4*)(C + (row0 + row) * (size_t)P + cg + cpos * 8) = v;
    }
}

// ---- fused edge MLP: embp dump + eu1(silu) + eu2, in-place lA reuse ----
__global__ __launch_bounds__(256, 3) void edge_mlp(
    const float* __restrict__ emb, const int* __restrict__ perm,
    const unsigned short* __restrict__ Wt1, const float* __restrict__ b1,
    const unsigned short* __restrict__ Wt2, const float* __restrict__ b2,
    unsigned short* __restrict__ embp, unsigned short* __restrict__ fup)
{
    __shared__ uint4 lA4[2048];
    char* lA = (char*)lA4;
    const int t = threadIdx.x;
    const size_t e0 = (size_t)blockIdx.x * 128;
    // stage emb[perm] -> lA (the pipeline's single reorder point)
#pragma unroll
    for (int i = 0; i < 16; ++i) {
        const int f4 = t + i * 256;
        const int r = f4 >> 5, c4 = f4 & 31;
        const size_t gr = (size_t)perm[e0 + r];
        const float4 v = ((const float4*)(emb + gr * 128))[c4];
        ushort4v bb;
        bb.x = f2bf(v.x); bb.y = f2bf(v.y); bb.z = f2bf(v.z); bb.w = f2bf(v.w);
        *(ushort4v*)(lA + ((r * 256 + c4 * 8) ^ ((r & 7) << 4))) = bb;
    }
    __syncthreads();
    // dump embp coalesced (full lines)
#pragma unroll
    for (int i = 0; i < 8; ++i) {
        const int ch = t + i * 256;
        const int row = ch >> 4, cpos = ch & 15;
        const uint4 v = *(const uint4*)(lA + ((row * 256 + cpos * 16) ^ ((row & 7) << 4)));
        *(uint4*)(embp + (e0 + row) * 128 + cpos * 8) = v;
    }
    const int lane = t & 63, wid = t >> 6;
    const int rbase = (wid >> 1) * 64, cbase = (wid & 1) * 64;
    const int lr = lane & 15, lgp = lane >> 4;
    f32x4 acc[4][4];
    // ---- GEMM1: silu(emb @ Weu1 + b1) ----
#pragma unroll
    for (int i = 0; i < 4; ++i)
#pragma unroll
        for (int j = 0; j < 4; ++j) acc[i][j] = (f32x4){0.f, 0.f, 0.f, 0.f};
#pragma unroll
    for (int ks = 0; ks < 4; ++ks) {
        bf16x8 av[4], bv[4];
#pragma unroll
        for (int mt = 0; mt < 4; ++mt) {
            const int r = rbase + mt * 16 + lr;
            av[mt] = *(const bf16x8*)(lA + ((r * 256 + ks * 64 + lgp * 16) ^ ((r & 7) << 4)));
        }
#pragma unroll
        for (int nt = 0; nt < 4; ++nt)
            bv[nt] = *(const bf16x8*)(Wt1 + (size_t)(cbase + nt * 16 + lr) * 128 + ks * 32 + lgp * 8);
#pragma unroll
        for (int mt = 0; mt < 4; ++mt)
#pragma unroll
            for (int nt = 0; nt < 4; ++nt)
                acc[mt][nt] = mfma16(bv[nt], av[mt], acc[mt][nt]);  // D[row via lr][col via lgp]
    }
    __syncthreads();   // all lA reads done -> safe to overwrite
    // repack silu(acc+b1) into lA (standard staging layout)
#pragma unroll
    for (int mt = 0; mt < 4; ++mt) {
        const int row = rbase + mt * 16 + lr;
#pragma unroll
        for (int nt = 0; nt < 4; ++nt) {
            const int col = cbase + nt * 16 + lgp * 4;
            const float4 b4 = *(const float4*)(b1 + col);
            ushort4v st;
            st.x = f2bf(silu_f(acc[mt][nt][0] + b4.x));
            st.y = f2bf(silu_f(acc[mt][nt][1] + b4.y));
            st.z = f2bf(silu_f(acc[mt][nt][2] + b4.z));
            st.w = f2bf(silu_f(acc[mt][nt][3] + b4.w));
            *(ushort4v*)(lA + ((row * 256 + col * 2) ^ ((row & 7) << 4))) = st;
        }
    }
    __syncthreads();
    // ---- GEMM2: (eu1out @ Weu2 + b2) ----
#pragma unroll
    for (int i = 0; i < 4; ++i)
#pragma unroll
        for (int j = 0; j < 4; ++j) acc[i][j] = (f32x4){0.f, 0.f, 0.f, 0.f};
#pragma unroll
    for (int ks = 0; ks < 4; ++ks) {
        bf16x8 av[4], bv[4];
#pragma unroll
        for (int mt = 0; mt < 4; ++mt) {
            const int r = rbase + mt * 16 + lr;
            av[mt] = *(const bf16x8*)(lA + ((r * 256 + ks * 64 + lgp * 16) ^ ((r & 7) << 4)));
        }
#pragma unroll
        for (int nt = 0; nt < 4; ++nt)
            bv[nt] = *(const bf16x8*)(Wt2 + (size_t)(cbase + nt * 16 + lr) * 128 + ks * 32 + lgp * 8);
#pragma unroll
        for (int mt = 0; mt < 4; ++mt)
#pragma unroll
            for (int nt = 0; nt < 4; ++nt)
                acc[mt][nt] = mfma16(bv[nt], av[mt], acc[mt][nt]);
    }
    __syncthreads();
    // repack acc+b2 into lA, then store fup coalesced
#pragma unroll
    for (int mt = 0; mt < 4; ++mt) {
        const int row = rbase + mt * 16 + lr;
#pragma unroll
        for (int nt = 0; nt < 4; ++nt) {
            const int col = cbase + nt * 16 + lgp * 4;
            const float4 b4 = *(const float4*)(b2 + col);
            ushort4v st;
            st.x = f2bf(acc[mt][nt][0] + b4.x);
            st.y = f2bf(acc[mt][nt][1] + b4.y);
            st.z = f2bf(acc[mt][nt][2] + b4.z);
            st.w = f2bf(acc[mt][nt][3] + b4.w);
            *(ushort4v*)(lA + ((row * 256 + col * 2) ^ ((row & 7) << 4))) = st;
        }
    }
    __syncthreads();
#pragma unroll
    for (int i = 0; i < 8; ++i) {
        const int ch = t + i * 256;
        const int row = ch >> 4, cpos = ch & 15;
        const uint4 v = *(const uint4*)(lA + ((row * 256 + cpos * 16) ^ ((row & 7) << 4)));
        *(uint4*)(fup + (e0 + row) * 128 + cpos * 8) = v;
    }
}

// ---- per-node CSR attention; rabp & attnw slot-ordered (sequential) ----
__global__ __launch_bounds__(256) void attn_kernel(
    const int* __restrict__ row_start, const int* __restrict__ srcp,
    const unsigned short* __restrict__ qkb, const unsigned short* __restrict__ rabp,
    const float* __restrict__ ewp, float* __restrict__ attnw)
{
    const int t = threadIdx.x;
    const int n = blockIdx.x * 4 + (t >> 6);
    const int lane = t & 63;
    const int el = lane >> 3, h = lane & 7;
    const int beg = row_start[n], end = row_start[n + 1];
    if (beg == end) return;
    const ushort8v q0 = *(const ushort8v*)(qkb + (size_t)n * 256 + h * 16);
    const ushort8v q1 = *(const ushort8v*)(qkb + (size_t)n * 256 + h * 16 + 8);
    float m = -1e30f, den = 0.f;
    for (int i0 = beg; i0 < end; i0 += 8) {
        const int i = i0 + el;
        const bool valid = i < end;
        const int ii = valid ? i : beg;
        const int s = srcp[ii];
        const ushort8v k0 = *(const ushort8v*)(qkb + (size_t)s * 256 + 128 + h * 16);
        const ushort8v k1 = *(const ushort8v*)(qkb + (size_t)s * 256 + 128 + h * 16 + 8);
        const ushort8v r0 = *(const ushort8v*)(rabp + (size_t)ii * 128 + h * 16);
        const ushort8v r1 = *(const ushort8v*)(rabp + (size_t)ii * 128 + h * 16 + 8);
        float lgv = 0.f;
#pragma unroll
        for (int j = 0; j < 8; ++j) lgv += bf2f(q0[j]) * bf2f(k0[j]) * bf2f(r0[j]);
#pragma unroll
        for (int j = 0; j < 8; ++j) lgv += bf2f(q1[j]) * bf2f(k1[j]) * bf2f(r1[j]);
        if (!valid) lgv = -1e30f;
        else attnw[(size_t)i * 8 + h] = lgv;
        float cm = lgv;
        cm = fmaxf(cm, __shfl_xor(cm, 8));
        cm = fmaxf(cm, __shfl_xor(cm, 16));
        cm = fmaxf(cm, __shfl_xor(cm, 32));
        const float nm = fmaxf(m, cm);
        float ex = valid ? __expf(lgv - nm) : 0.f;
        float cd = ex;
        cd += __shfl_xor(cd, 8);
        cd += __shfl_xor(cd, 16);
        cd += __shfl_xor(cd, 32);
        den = den * __expf(m - nm) + cd;
        m = nm;
    }
    const float sc = sqrtf((float)(end - beg)) * 0.08838834764831845f / den;
    for (int i0 = beg; i0 < end; i0 += 8) {
        const int i = i0 + el;
        if (i >= end) continue;
        const float w = ewp[i];
        const float cut = (w < 5.0f) ? 0.5f * (cosf(w * 0.62831853071795864f) + 1.0f) : 0.0f;
        const float lgv = attnw[(size_t)i * 8 + h];
        attnw[(size_t)i * 8 + h] = __expf(lgv - m) * sc * cut;
    }
}

// ---- fused r_ij MFMA GEMM + x_ij epilogue, slot-sequential ----
// blockIdx.y selects output col-group: shorter serial chain per block, 3x blocks.
// per-wave private LDS repack -> full-line 128B-contiguous ob row stores.
__global__ __launch_bounds__(256, 3) void combine_mfma(
    const unsigned short* __restrict__ embp, const unsigned short* __restrict__ Wt_re,
    const float* __restrict__ bre, const float* __restrict__ attnw,
    unsigned short* __restrict__ ob)
{
    __shared__ uint4 lA4[2048];
    __shared__ float attnS[128 * 8];
    __shared__ uint4 scr4[512];   // 8KB, 2KB per wave (private)
    char* lA = (char*)lA4;
    const int t = threadIdx.x;
    const size_t e0 = (size_t)blockIdx.x * 128;
    const int cg3 = blockIdx.y;
    {
        const uint4* Ag = (const uint4*)(embp + e0 * 128);
#pragma unroll
        for (int i = 0; i < 8; ++i) {
            const int chunk = t + i * 256;
            const int r = chunk >> 4, c16 = chunk & 15;
            *(uint4*)(lA + ((r * 256 + c16 * 16) ^ ((r & 7) << 4))) = Ag[chunk];
        }
    }
    ((float4*)attnS)[t] = ((const float4*)(attnw + e0 * 8))[t];
    __syncthreads();
    const int lane = t & 63, wid = t >> 6;
    const int rbase = (wid >> 1) * 64, cbase = (wid & 1) * 64;
    const int lr = lane & 15, lgp = lane >> 4;
    char* swr = (char*)scr4 + wid * 2048;
    const int r2 = lane >> 3, c16r = lane & 7;
    const unsigned short* Wp = Wt_re + (size_t)cg3 * 16384;
    f32x4 acc[4][4];
#pragma unroll
    for (int i = 0; i < 4; ++i)
#pragma unroll
        for (int j = 0; j < 4; ++j) acc[i][j] = (f32x4){0.f, 0.f, 0.f, 0.f};
#pragma unroll
    for (int ks = 0; ks < 4; ++ks) {
        bf16x8 av[4], bv[4];
#pragma unroll
        for (int mt = 0; mt < 4; ++mt) {
            const int r = rbase + mt * 16 + lr;
            av[mt] = *(const bf16x8*)(lA + ((r * 256 + ks * 64 + lgp * 16) ^ ((r & 7) << 4)));
        }
#pragma unroll
        for (int nt = 0; nt < 4; ++nt)
            bv[nt] = *(const bf16x8*)(Wp + (size_t)(cbase + nt * 16 + lr) * 128 + ks * 32 + lgp * 8);
#pragma unroll
        for (int mt = 0; mt < 4; ++mt)
#pragma unroll
            for (int nt = 0; nt < 4; ++nt)
                acc[mt][nt] = mfma16(bv[nt], av[mt], acc[mt][nt]);  // swapped: D[c][r]
    }
    const int cgo = cg3 * 128;
#pragma unroll
    for (int mt = 0; mt < 4; ++mt) {
        const int row = rbase + mt * 16 + lr;
        const float* aS = attnS + row * 8;
#pragma unroll
        for (int nt = 0; nt < 4; ++nt) {
            const int wc = nt * 16 + lgp * 4;
            const int gcol = cgo + cbase + wc;
            const float coef = aS[gcol / 48];
            const float4 b4 = *(const float4*)(bre + gcol);
            ushort4v st;
            st.x = f2bf((acc[mt][nt][0] + b4.x) * coef);
            st.y = f2bf((acc[mt][nt][1] + b4.y) * coef);
            st.z = f2bf((acc[mt][nt][2] + b4.z) * coef);
            st.w = f2bf((acc[mt][nt][3] + b4.w) * coef);
            *(ushort4v*)(swr + ((lr * 128 + wc * 2) ^ ((lr & 7) << 4))) = st;
        }
#pragma unroll
        for (int i = 0; i < 2; ++i) {
            const int rr = r2 + i * 8;
            const uint4 v = *(const uint4*)(swr + ((rr * 128 + c16r * 16) ^ ((rr & 7) << 4)));
            const size_t row_g = e0 + rbase + mt * 16 + rr;
            *(uint4*)(ob + row_g * 384 + cgo + cbase + c16r * 8) = v;
        }
    }
}

// ---- fused (wd + w_dot GEMM + tanh/df), per-wave repack, full-line df stores ----
__global__ __launch_bounds__(256, 3) void wdot_fused(
    const unsigned short* __restrict__ w12, const int* __restrict__ srcp,
    const int* __restrict__ dstp, const float* __restrict__ evp,
    const unsigned short* __restrict__ Wt_lin, const float* __restrict__ bl,
    const unsigned short* __restrict__ embp, const unsigned short* __restrict__ fup,
    const int* __restrict__ perm, float* __restrict__ df)
{
    __shared__ uint4 lA4[2048];
    char* lA = (char*)lA4;
    const int t = threadIdx.x;
    const size_t e0 = (size_t)blockIdx.x * 128;
#pragma unroll
    for (int i = 0; i < 8; ++i) {
        const int chunk = t + i * 256;
        const int r = chunk >> 4, c8 = chunk & 15;
        const size_t slot = e0 + r;
        const int s = srcp[slot], d = dstp[slot];
        const float e0v = evp[slot * 3 + 0], e1v = evp[slot * 3 + 1], e2v = evp[slot * 3 + 2];
        const ushort8v a0 = *(const ushort8v*)(w12 + ((size_t)d * 3 + 0) * 256 + c8 * 8);
        const ushort8v a1 = *(const ushort8v*)(w12 + ((size_t)d * 3 + 1) * 256 + c8 * 8);
        const ushort8v a2 = *(const ushort8v*)(w12 + ((size_t)d * 3 + 2) * 256 + c8 * 8);
        const ushort8v c0 = *(const ushort8v*)(w12 + ((size_t)s * 3 + 0) * 256 + 128 + c8 * 8);
        const ushort8v c1 = *(const ushort8v*)(w12 + ((size_t)s * 3 + 1) * 256 + 128 + c8 * 8);
        const ushort8v c2 = *(const ushort8v*)(w12 + ((size_t)s * 3 + 2) * 256 + 128 + c8 * 8);
        ushort8v o;
#pragma unroll
        for (int j = 0; j < 8; ++j) {
            const float av = e0v * bf2f(a0[j]) + e1v * bf2f(a1[j]) + e2v * bf2f(a2[j]);
            const float bv = e0v * bf2f(c0[j]) + e1v * bf2f(c1[j]) + e2v * bf2f(c2[j]);
            o[j] = f2bf(av * bv);
        }
        *(ushort8v*)(lA + ((r * 256 + c8 * 16) ^ ((r & 7) << 4))) = o;
    }
    __syncthreads();
    const int lane = t & 63, wid = t >> 6;
    const int rbase = (wid >> 1) * 64, cbase = (wid & 1) * 64;
    const int lr = lane & 15, lgp = lane >> 4;
    f32x4 acc[4][4];
#pragma unroll
    for (int i = 0; i < 4; ++i)
#pragma unroll
        for (int j = 0; j < 4; ++j) acc[i][j] = (f32x4){0.f, 0.f, 0.f, 0.f};
#pragma unroll
    for (int ks = 0; ks < 4; ++ks) {
        bf16x8 av[4], bv[4];
#pragma unroll
        for (int mt = 0; mt < 4; ++mt) {
            const int r = rbase + mt * 16 + lr;
            av[mt] = *(const bf16x8*)(lA + ((r * 256 + ks * 64 + lgp * 16) ^ ((r & 7) << 4)));
        }
#pragma unroll
        for (int nt = 0; nt < 4; ++nt)
            bv[nt] = *(const bf16x8*)(Wt_lin + (size_t)(cbase + nt * 16 + lr) * 128 + ks * 32 + lgp * 8);
#pragma unroll
        for (int mt = 0; mt < 4; ++mt)
#pragma unroll
            for (int nt = 0; nt < 4; ++nt)
                acc[mt][nt] = mfma16(bv[nt], av[mt], acc[mt][nt]);  // swapped
    }
    __syncthreads();   // all waves done reading lA; reuse as private repack scratch
    char* swr = lA + wid * 8192;
    const int r2 = lane >> 2, c4 = lane & 3;
#pragma unroll
    for (int mt = 0; mt < 4; ++mt) {
#pragma unroll
        for (int nt = 0; nt < 4; ++nt) {
            const int wc = nt * 16 + lgp * 4;
            const float4 b4 = *(const float4*)(bl + cbase + wc);
            float4 v;
            v.x = tanhf(acc[mt][nt][0] + b4.x);
            v.y = tanhf(acc[mt][nt][1] + b4.y);
            v.z = tanhf(acc[mt][nt][2] + b4.z);
            v.w = tanhf(acc[mt][nt][3] + b4.w);
            *(float4*)(swr + ((lr * 256 + wc * 4) ^ ((lr & 7) << 4))) = v;
        }
#pragma unroll
        for (int i = 0; i < 4; ++i) {
            const int chunk = i * 4 + c4;
            const float4 v = *(const float4*)(swr + ((r2 * 256 + chunk * 16) ^ ((r2 & 7) << 4)));
            const int row = rbase + mt * 16 + r2;
            const size_t sbase = (e0 + row) * 128 + cbase + chunk * 4;
            const ushort4v em = *(const ushort4v*)(embp + sbase);
            const ushort4v fu = *(const ushort4v*)(fup + sbase);
            const size_t orow = (size_t)perm[e0 + row];
            float4 o;
            o.x = bf2f(em.x) + bf2f(fu.x) * v.x;
            o.y = bf2f(em.y) + bf2f(fu.y) * v.y;
            o.z = bf2f(em.z) + bf2f(fu.z) * v.z;
            o.w = bf2f(em.w) + bf2f(fu.w) * v.w;
            *(float4*)(df + orow * 128 + cbase + chunk * 4) = o;
        }
    }
}

// ---- CSR build ----
__global__ __launch_bounds__(256) void hist_kernel(const int* __restrict__ dst, int* __restrict__ counts) {
    const int e = blockIdx.x * 256 + threadIdx.x;
    atomicAdd(&counts[dst[e]], 1);
}

__global__ __launch_bounds__(256) void scan_kernel(const int* __restrict__ counts,
                                                   int* __restrict__ row_start,
                                                   int* __restrict__ cursor) {
    __shared__ int part[256];
    const int t = threadIdx.x;
    const int base = t * 64;
    int local[64];
    int s = 0;
#pragma unroll
    for (int i = 0; i < 64; ++i) { local[i] = s; s += counts[base + i]; }
    part[t] = s;
    __syncthreads();
    for (int off = 1; off < 256; off <<= 1) {
        int v = (t >= off) ? part[t - off] : 0;
        __syncthreads();
        part[t] += v;
        __syncthreads();
    }
    const int prev = (t == 0) ? 0 : part[t - 1];
#pragma unroll
    for (int i = 0; i < 64; ++i) {
        const int v = prev + local[i];
        row_start[base + i] = v;
        cursor[base + i] = v;
    }
    if (t == 255) row_start[NN] = prev + s;
}

// fill: perm + slot-ordered src/dst/ewt/ev
__global__ __launch_bounds__(256) void fill_kernel(
    const int* __restrict__ src, const int* __restrict__ dst,
    const float* __restrict__ ewt, const float* __restrict__ ev,
    int* __restrict__ cursor, int* __restrict__ perm, int* __restrict__ srcp,
    int* __restrict__ dstp, float* __restrict__ ewp, float* __restrict__ evp)
{
    const int e = blockIdx.x * 256 + threadIdx.x;
    const int d = dst[e];
    const int p = atomicAdd(&cursor[d], 1);
    perm[p] = e;
    srcp[p] = src[e];
    dstp[p] = d;
    ewp[p] = ewt[e];
    evp[p * 3 + 0] = ev[e * 3 + 0];
    evp[p * 3 + 1] = ev[e * 3 + 1];
    evp[p * 3 + 2] = ev[e * 3 + 2];
}

// ---- gather: 4 nodes/block, 64 lanes/node, 2 bf16 per lane (uint loads) ----
__global__ __launch_bounds__(256) void gather_kernel(
    const int* __restrict__ row_start, const int* __restrict__ srcp,
    const unsigned short* __restrict__ ob, const unsigned short* __restrict__ xv,
    const unsigned short* __restrict__ mub, const float* __restrict__ evp,
    const float* __restrict__ h_in, const float* __restrict__ mu_in,
    float* __restrict__ h_out, float* __restrict__ mu_out)
{
    const int n = blockIdx.x * 4 + (threadIdx.x >> 6);
    const int t2 = (threadIdx.x & 63) * 2;
    const int beg = row_start[n], end = row_start[n + 1];
    float2 h2 = *(const float2*)(h_in + (size_t)n * 128 + t2);
    float2 m0 = *(const float2*)(mu_in + (size_t)n * 384 + t2);
    float2 m1 = *(const float2*)(mu_in + (size_t)n * 384 + 128 + t2);
    float2 m2 = *(const float2*)(mu_in + (size_t)n * 384 + 256 + t2);
#define GSTEP(i)  { \
        const int s = srcp[i]; \
        const float ev0 = evp[(i) * 3 + 0], ev1 = evp[(i) * 3 + 1], ev2 = evp[(i) * 3 + 2]; \
        const unsigned op0 = *(const unsigned*)(ob + (size_t)(i) * 384 + t2); \
        const unsigned op1 = *(const unsigned*)(ob + (size_t)(i) * 384 + 128 + t2); \
        const unsigned op2 = *(const unsigned*)(ob + (size_t)(i) * 384 + 256 + t2); \
        const unsigned xp0 = *(const unsigned*)(xv + (size_t)s * 384 + t2); \
        const unsigned xp1 = *(const unsigned*)(xv + (size_t)s * 384 + 128 + t2); \
        const unsigned xp2 = *(const unsigned*)(xv + (size_t)s * 384 + 256 + t2); \
        const unsigned mp0 = *(const unsigned*)(mub + (size_t)s * 384 + t2); \
        const unsigned mp1 = *(const unsigned*)(mub + (size_t)s * 384 + 128 + t2); \
        const unsigned mp2 = *(const unsigned*)(mub + (size_t)s * 384 + 256 + t2); \
        const float os0 = bf2f((unsigned short)op0) * bf2f((unsigned short)xp0); \
        const float os1 = bf2f((unsigned short)(op0 >> 16)) * bf2f((unsigned short)(xp0 >> 16)); \
        const float od0 = bf2f((unsigned short)op1) * bf2f((unsigned short)xp1); \
        const float od1 = bf2f((unsigned short)(op1 >> 16)) * bf2f((unsigned short)(xp1 >> 16)); \
        const float ot0 = bf2f((unsigned short)op2) * bf2f((unsigned short)xp2); \
        const float ot1 = bf2f((unsigned short)(op2 >> 16)) * bf2f((unsigned short)(xp2 >> 16)); \
        h2.x += os0; h2.y += os1; \
        m0.x += od0 * ev0 + ot0 * bf2f((unsigned short)mp0); \
        m0.y += od1 * ev0 + ot1 * bf2f((unsigned short)(mp0 >> 16)); \
        m1.x += od0 * ev1 + ot0 * bf2f((unsigned short)mp1); \
        m1.y += od1 * ev1 + ot1 * bf2f((unsigned short)(mp1 >> 16)); \
        m2.x += od0 * ev2 + ot0 * bf2f((unsigned short)mp2); \
        m2.y += od1 * ev2 + ot1 * bf2f((unsigned short)(mp2 >> 16)); \
    }
    int i = beg;
    for (; i + 1 < end; i += 2) { GSTEP(i); GSTEP(i + 1); }
    if (i < end) GSTEP(i);
#undef GSTEP
    *(float2*)(h_out + (size_t)n * 128 + t2) = h2;
    *(float2*)(mu_out + (size_t)n * 384 + t2) = m0;
    *(float2*)(mu_out + (size_t)n * 384 + 128 + t2) = m1;
    *(float2*)(mu_out + (size_t)n * 384 + 256 + t2) = m2;
}

extern "C" void kernel_launch(void* const* d_in, const int* in_sizes, int n_in,
                              void* d_out, int out_size, void* d_ws, size_t ws_size,
                              hipStream_t stream) {
    const int* eidx = (const int*)d_in[0];
    const int* src = eidx;
    const int* dst = eidx + EE;
    const float* h_in  = (const float*)d_in[1];
    const float* mu_in = (const float*)d_in[2];
    const float* ev    = (const float*)d_in[3];
    const float* emb   = (const float*)d_in[4];
    const float* ewt   = (const float*)d_in[5];
    const float* W_q   = (const float*)d_in[7];  const float* b_q   = (const float*)d_in[8];
    const float* W_k   = (const float*)d_in[9];  const float* b_k   = (const float*)d_in[10];
    const float* W_gs1 = (const float*)d_in[11]; const float* b_gs1 = (const float*)d_in[12];
    const float* W_gs2 = (const float*)d_in[13]; const float* b_gs2 = (const float*)d_in[14];
    const float* W_gv1 = (const float*)d_in[15]; const float* b_gv1 = (const float*)d_in[16];
    const float* W_gv2 = (const float*)d_in[17]; const float* b_gv2 = (const float*)d_in[18];
    const float* W_phik= (const float*)d_in[19]; const float* b_phik= (const float*)d_in[20];
    const float* W_re  = (const float*)d_in[21]; const float* b_re  = (const float*)d_in[22];
    const float* W_vq  = (const float*)d_in[23];
    const float* W_vk0 = (const float*)d_in[24];
    const float* W_lin = (const float*)d_in[25]; const float* b_lin = (const float*)d_in[26];
    const float* W_eu1 = (const float*)d_in[27]; const float* b_eu1 = (const float*)d_in[28];
    const float* W_eu2 = (const float*)d_in[29]; const float* b_eu2 = (const float*)d_in[30];

    float* out    = (float*)d_out;
    float* h_out  = out;
    float* mu_out = out + (size_t)NN * ZZ;
    float* df     = out + (size_t)NN * ZZ * 4;

    const size_t NZ = (size_t)NN * ZZ, N3Z = (size_t)NN * 3 * ZZ, EZ = (size_t)EE * ZZ;
    const size_t EH = (size_t)EE * HH;
    char* p = (char*)d_ws;
    unsigned short* qkb   = (unsigned short*)p; p += NZ * 2 * 2;   // N x 256 (q|k)
    unsigned short* tmpn2 = (unsigned short*)p; p += NZ * 2 * 2;   // N x 256 (gs1|gv1)
    unsigned short* x3b   = (unsigned short*)p; p += N3Z * 2;      // N x 384
    unsigned short* xv    = (unsigned short*)p; p += N3Z * 2;      // N x 384
    unsigned short* mub   = (unsigned short*)p; p += N3Z * 2;      // N x 384 bf16 mu
    unsigned short* w12   = (unsigned short*)p; p += N3Z * 2 * 2;  // 3N x 256 (w1|w2)
    unsigned short* embp  = (unsigned short*)p; p += EZ * 2;       // slot-order bf16 emb
    unsigned short* rabp  = (unsigned short*)p; p += EZ * 2;       // slot-order r_attn
    unsigned short* fup   = (unsigned short*)p; p += EZ * 2;       // slot-order f_up
    unsigned short* ob    = (unsigned short*)p; p += EZ * 3 * 2;   // E x 384 slot-order
    float* attnw          = (float*)p;          p += EH * 4;       // slot-indexed coef
    unsigned short* wt    = (unsigned short*)p; p += 2432 * 128 * 2;
    float* bcat           = (float*)p;          p += 2432 * 4;
    int* counts           = (int*)p;            p += NN * 4;
    int* cursor           = (int*)p;            p += NN * 4;
    int* row_start        = (int*)p;            p += (NN + 1) * 4;
    int* perm             = (int*)p;            p += EE * 4;
    int* srcp             = (int*)p;            p += EE * 4;
    int* dstp             = (int*)p;            p += EE * 4;
    float* ewp            = (float*)p;          p += EE * 4;
    float* evp            = (float*)p;          p += EE * 12;

    // pool order: q,k,gs1,gv1,gs2,gv2,phik,re,vq,vk0,lin,eu1,eu2
    const float* wsrc[13] = {W_q, W_k, W_gs1, W_gv1, W_gs2, W_gv2, W_phik,
                             W_re, W_vq, W_vk0, W_lin, W_eu1, W_eu2};
    const float* bsrc[13] = {b_q, b_k, b_gs1, b_gv1, b_gs2, b_gv2, b_phik,
                             b_re, nullptr, nullptr, b_lin, b_eu1, b_eu2};
    const int Ps[13] = {128, 128, 128, 128, 384, 384, 128, 384, 128, 128, 128, 128, 128};
    WPrep wp; BPrep bp;
    int tiles = 0;
    for (int i = 0; i < 13; ++i) {
        wp.w[i] = wsrc[i]; wp.P[i] = Ps[i]; wp.tile0[i] = tiles;
        bp.b[i] = bsrc[i]; bp.off[i] = tiles * 128;
        tiles += Ps[i] / 128;
    }
    wp.tile0[13] = tiles; bp.off[13] = tiles * 128;
    unsigned short* wT[13]; const float* bC[13];
    for (int i = 0; i < 13; ++i) { wT[i] = wt + (size_t)wp.tile0[i] * 16384; bC[i] = bcat + bp.off[i]; }

    dim3 blk(256);
    prep_weights<<<dim3(tiles), dim3(128), 0, stream>>>(wp, wt);
    prep_bias<<<dim3(10), blk, 0, stream>>>(bp, bcat);
    prep_mub<<<dim3(N3Z / 8 / 256), blk, 0, stream>>>(mu_in, mub);
    // CSR build first (edge pipeline is slot-ordered from the source)
    hipMemsetAsync(counts, 0, NN * 4, stream);
    hist_kernel<<<dim3(EE/256), blk, 0, stream>>>(dst, counts);
    scan_kernel<<<dim3(1), blk, 0, stream>>>(counts, row_start, cursor);
    fill_kernel<<<dim3(EE/256), blk, 0, stream>>>(src, dst, ewt, ev, cursor, perm, srcp, dstp, ewp, evp);
    // node-side GEMMs (merged)
    mm_bf16<0,0,0,0><<<dim3(NN/128, 2), blk, 0, stream>>>(h_in, wT[0], bC[0], qkb, nullptr, nullptr, nullptr, 256, 128);
    mm_bf16<1,0,0,0><<<dim3(NN/128, 2), blk, 0, stream>>>(h_in, wT[2], bC[2], tmpn2, nullptr, nullptr, nullptr, 256, 128);
    mm_bf16<0,1,0,0><<<dim3(NN/128, 3), blk, 0, stream>>>(tmpn2, wT[4], bC[4], x3b, nullptr, nullptr, nullptr, 384, 256);
    mm_bf16<2,1,0,0><<<dim3(NN/128, 3), blk, 0, stream>>>(tmpn2 + 128, wT[5], bC[5], xv, x3b, nullptr, nullptr, 384, 256);
    // edge-side: fused eu1+eu2 (dumps embp; fup out), then phik from embp
    edge_mlp<<<dim3(EE/128), blk, 0, stream>>>(emb, perm, wT[11], bC[11], wT[12], bC[12], embp, fup);
    mm_bf16<1,1,0,0><<<dim3(EE/128, 1), blk, 0, stream>>>(embp, wT[6], bC[6], rabp, nullptr, nullptr, nullptr, 128, 128);
    // per-node CSR attention -> slot coef (all sequential)
    attn_kernel<<<dim3(NN/4), blk, 0, stream>>>(row_start, srcp, qkb, rabp, ewp, attnw);
    // fused r_ij GEMM + x_ij epilogue (grid.y=3: one col-group per block)
    combine_mfma<<<dim3(EE/128, 3), blk, 0, stream>>>(embp, wT[7], bC[7], attnw, ob);
    // atomic-free gather: sequential ob stream, 2-wide lanes
    gather_kernel<<<dim3(NN/4), blk, 0, stream>>>(
        row_start, srcp, ob, xv, mub, evp, h_in, mu_in, h_out, mu_out);
    // vector branch: merged vq|vk0, then wdot (df scattered full-line rows via perm)
    mm_bf16<0,0,0,0><<<dim3(3*NN/128, 2), blk, 0, stream>>>(mu_out, wT[8], bC[8], w12, nullptr, nullptr, nullptr, 256, 128);
    wdot_fused<<<dim3(EE/128), blk, 0, stream>>>(
        w12, srcp, dstp, evp, wT[10], bC[10], embp, fup, perm, df);
}